// Round 3
// baseline (581.659 us; speedup 1.0000x reference)
//
#include <hip/hip_runtime.h>
#include <hip/hip_bf16.h>

typedef __attribute__((ext_vector_type(8))) __bf16 bf16x8;
typedef __attribute__((ext_vector_type(4))) float f32x4;

#define MFMA_BF16 __builtin_amdgcn_mfma_f32_16x16x32_bf16

static __device__ __forceinline__ unsigned short f2bf(float f) {
  unsigned int u = __builtin_bit_cast(unsigned int, f);
  u += 0x7fffu + ((u >> 16) & 1u);
  return (unsigned short)(u >> 16);
}

// ---------- fp32 -> bf16 cast, 8 elems/thread ----------
__global__ __launch_bounds__(256) void cast_bf16_k(const float* __restrict__ in,
                                                   unsigned short* __restrict__ out,
                                                   int n8) {
  int i = blockIdx.x * 256 + threadIdx.x;
  if (i >= n8) return;
  const float4* p = (const float4*)in + (size_t)i * 2;
  float4 a = p[0], b = p[1];
  ushort4 r0, r1;
  r0.x = f2bf(a.x); r0.y = f2bf(a.y); r0.z = f2bf(a.z); r0.w = f2bf(a.w);
  r1.x = f2bf(b.x); r1.y = f2bf(b.y); r1.z = f2bf(b.z); r1.w = f2bf(b.w);
  ushort4* q = (ushort4*)out + (size_t)i * 2;
  q[0] = r0; q[1] = r1;
}

// ---------- RoPE cos/sin table: [2048][32] float2 ----------
__global__ __launch_bounds__(256) void rope_tab_k(const int* __restrict__ pos,
                                                  float2* __restrict__ tab) {
  int t = blockIdx.x * 256 + threadIdx.x;  // 65536 total
  int s = t >> 5, k = t & 31;
  float p = (float)pos[s];
  float inv = powf(10000.0f, -(float)(2 * k) / 64.0f);
  float ang = p * inv;
  tab[t] = make_float2(cosf(ang), sinf(ang));
}

// ---------- bf16 GEMM: C[M][N] = A[M][K] * B^T, B given as [N][K] ----------
// MODE 0: A=x_bf16, z selects w_{q,k,v}; epilogue: RoPE (z<2), scale Q by 1/8,
//         bf16 scatter to per-head [b][h][s][d] layout.
// MODE 1: A=O_bf16, W=w_o_bf16; fp32 store to Cout.
template <int MODE>
__global__ __launch_bounds__(256) void gemm_bt(
    const unsigned short* __restrict__ A, const unsigned short* __restrict__ W,
    unsigned short* __restrict__ Qb, unsigned short* __restrict__ Kb,
    unsigned short* __restrict__ Vb, float* __restrict__ Cout,
    const float2* __restrict__ rtab) {
  __shared__ unsigned short As[128 * 64];
  __shared__ unsigned short Bs[128 * 64];
  const int tid = threadIdx.x;
  const int lane = tid & 63;
  const int w = tid >> 6;          // wave 0..3
  const int wr = w >> 1, wc = w & 1;
  const int hi = lane >> 4, lo = lane & 15;
  const int m0 = blockIdx.x * 128;
  const int n0 = blockIdx.y * 128;
  const int z = blockIdx.z;
  const unsigned short* Bmat = W + (size_t)z * 1024 * 1024;

  const int sr = lane >> 3;        // staging row within 8-row chunk
  const int sc8 = (lane & 7) * 8;  // staging col (elements)

  f32x4 acc[4][4] = {};

  for (int kt = 0; kt < 16; ++kt) {
    const int kofs = kt * 64;
#pragma unroll
    for (int c = 0; c < 4; ++c) {
      const int rowA = c * 32 + w * 8;
      const unsigned short* ga = A + (size_t)(m0 + rowA + sr) * 1024 + kofs + sc8;
      __builtin_amdgcn_global_load_lds(
          (const __attribute__((address_space(1))) void*)ga,
          (__attribute__((address_space(3))) void*)&As[rowA * 64], 16, 0, 0);
      const unsigned short* gb = Bmat + (size_t)(n0 + rowA + sr) * 1024 + kofs + sc8;
      __builtin_amdgcn_global_load_lds(
          (const __attribute__((address_space(1))) void*)gb,
          (__attribute__((address_space(3))) void*)&Bs[rowA * 64], 16, 0, 0);
    }
    __syncthreads();
#pragma unroll
    for (int kb = 0; kb < 2; ++kb) {
      bf16x8 af[4], bfr[4];
#pragma unroll
      for (int mt = 0; mt < 4; ++mt)
        af[mt] = *(const bf16x8*)&As[(wr * 64 + mt * 16 + lo) * 64 + kb * 32 + hi * 8];
#pragma unroll
      for (int nt = 0; nt < 4; ++nt)
        bfr[nt] = *(const bf16x8*)&Bs[(wc * 64 + nt * 16 + lo) * 64 + kb * 32 + hi * 8];
#pragma unroll
      for (int mt = 0; mt < 4; ++mt)
#pragma unroll
        for (int nt = 0; nt < 4; ++nt)
          acc[mt][nt] = MFMA_BF16(af[mt], bfr[nt], acc[mt][nt], 0, 0, 0);
    }
    __syncthreads();
  }

  // Epilogue. C/D layout: row = (lane>>4)*4 + j, col = lane&15 (verified m89/m91).
#pragma unroll
  for (int mt = 0; mt < 4; ++mt) {
#pragma unroll
    for (int nt = 0; nt < 4; ++nt) {
      const int c = n0 + wc * 64 + nt * 16 + lo;
#pragma unroll
      for (int j = 0; j < 4; ++j) {
        const int r = m0 + wr * 64 + mt * 16 + hi * 4 + j;
        float v = acc[mt][nt][j];
        if constexpr (MODE == 1) {
          Cout[(size_t)r * 1024 + c] = v;
        } else {
          const float other = __shfl_xor(v, 1);  // partner column (c^1)
          const int b = r >> 11, s = r & 2047;
          const int h = c >> 6, dd = c & 63;
          float outv;
          if (z < 2) {  // RoPE for Q,K
            float2 cs = rtab[s * 32 + (dd >> 1)];
            outv = (dd & 1) ? (cs.y * other + cs.x * v)
                            : (cs.x * v - cs.y * other);
            if (z == 0) outv *= 0.125f;  // fold softmax scale into Q (exact pow2)
          } else {
            outv = v;
          }
          unsigned short* dst = (z == 0) ? Qb : (z == 1) ? Kb : Vb;
          dst[((size_t)(b * 16 + h) * 2048 + s) * 64 + dd] = f2bf(outv);
        }
      }
    }
  }
}

// ---------- causal flash attention: 4 waves, 64 Q-rows/block, KV tile 64 ----------
__global__ __launch_bounds__(256) void attn_k(const unsigned short* __restrict__ Qb,
                                              const unsigned short* __restrict__ Kb,
                                              const unsigned short* __restrict__ Vb,
                                              unsigned short* __restrict__ Ob) {
  __shared__ unsigned short Kl[64 * 72];      // K tile [kpos][d], +8 pad
  __shared__ unsigned short Vt[64 * 72];      // V^T tile [d][kpos], +8 pad
  __shared__ unsigned short Pl[4 * 16 * 72];  // per-wave P [16][64], +8 pad
  const int tid = threadIdx.x;
  const int lane = tid & 63;
  const int w = tid >> 6;
  const int hi = lane >> 4, lo = lane & 15;
  const int qt = blockIdx.x;   // 0..31
  const int bh = blockIdx.y;   // 0..63 (b*16+h)
  const int qbase = qt * 64;
  const unsigned short* Qp = Qb + (size_t)bh * 2048 * 64;
  const unsigned short* Kp = Kb + (size_t)bh * 2048 * 64;
  const unsigned short* Vp = Vb + (size_t)bh * 2048 * 64;

  bf16x8 qf[2];
  {
    const int qrow = qbase + w * 16 + lo;
    qf[0] = *(const bf16x8*)&Qp[(size_t)qrow * 64 + hi * 8];
    qf[1] = *(const bf16x8*)&Qp[(size_t)qrow * 64 + 32 + hi * 8];
  }

  f32x4 oacc[4] = {};
  float mrow[4], lrow[4];
#pragma unroll
  for (int j = 0; j < 4; ++j) { mrow[j] = -1e30f; lrow[j] = 0.0f; }

  const int srow = tid >> 3, scol = (tid & 7) * 8;
  const int vrow = tid >> 4, vc = (tid & 15) * 4;
  unsigned short* Pw = &Pl[w * 16 * 72];

  for (int kt = 0; kt <= qt; ++kt) {
    __syncthreads();  // prior iteration's PV reads done before restage
    // stage K tile (coalesced 16B)
#pragma unroll
    for (int r2 = 0; r2 < 2; ++r2) {
      const int row = r2 * 32 + srow;
      uint4 d = *(const uint4*)&Kp[(size_t)(kt * 64 + row) * 64 + scol];
      *(uint4*)&Kl[row * 72 + scol] = d;
    }
    // stage V transposed (coalesced read, u16 scatter write)
#pragma unroll
    for (int r2 = 0; r2 < 4; ++r2) {
      const int k = r2 * 16 + vrow;
      uint2 d = *(const uint2*)&Vp[(size_t)(kt * 64 + k) * 64 + vc];
      Vt[(vc + 0) * 72 + k] = (unsigned short)(d.x & 0xffff);
      Vt[(vc + 1) * 72 + k] = (unsigned short)(d.x >> 16);
      Vt[(vc + 2) * 72 + k] = (unsigned short)(d.y & 0xffff);
      Vt[(vc + 3) * 72 + k] = (unsigned short)(d.y >> 16);
    }
    __syncthreads();

    // QK^T: scores 16x64 per wave (Q pre-scaled by 1/8)
    f32x4 sc[4] = {};
#pragma unroll
    for (int ct = 0; ct < 4; ++ct) {
      bf16x8 kf0 = *(const bf16x8*)&Kl[(ct * 16 + lo) * 72 + hi * 8];
      bf16x8 kf1 = *(const bf16x8*)&Kl[(ct * 16 + lo) * 72 + 32 + hi * 8];
      sc[ct] = MFMA_BF16(qf[0], kf0, sc[ct], 0, 0, 0);
      sc[ct] = MFMA_BF16(qf[1], kf1, sc[ct], 0, 0, 0);
    }

    if (kt == qt) {  // diagonal tile: causal mask
#pragma unroll
      for (int ct = 0; ct < 4; ++ct)
#pragma unroll
        for (int j = 0; j < 4; ++j) {
          const int kpos = kt * 64 + ct * 16 + lo;
          const int qpos = qbase + w * 16 + hi * 4 + j;
          if (kpos > qpos) sc[ct][j] = -1e30f;
        }
    }

    // online softmax (rows live in 16-lane groups; shfl_xor<16 stays in-group)
    float tmax[4];
#pragma unroll
    for (int j = 0; j < 4; ++j)
      tmax[j] = fmaxf(fmaxf(sc[0][j], sc[1][j]), fmaxf(sc[2][j], sc[3][j]));
#pragma unroll
    for (int d = 1; d < 16; d <<= 1)
#pragma unroll
      for (int j = 0; j < 4; ++j)
        tmax[j] = fmaxf(tmax[j], __shfl_xor(tmax[j], d));

    float mnew[4], alpha[4];
#pragma unroll
    for (int j = 0; j < 4; ++j) {
      mnew[j] = fmaxf(mrow[j], tmax[j]);
      alpha[j] = __expf(mrow[j] - mnew[j]);
      mrow[j] = mnew[j];
    }
    float rsum[4] = {0.f, 0.f, 0.f, 0.f};
#pragma unroll
    for (int ct = 0; ct < 4; ++ct)
#pragma unroll
      for (int j = 0; j < 4; ++j) {
        float p = __expf(sc[ct][j] - mnew[j]);
        sc[ct][j] = p;
        rsum[j] += p;
      }
#pragma unroll
    for (int d = 1; d < 16; d <<= 1)
#pragma unroll
      for (int j = 0; j < 4; ++j)
        rsum[j] += __shfl_xor(rsum[j], d);
#pragma unroll
    for (int j = 0; j < 4; ++j)
      lrow[j] = lrow[j] * alpha[j] + rsum[j];
#pragma unroll
    for (int dt = 0; dt < 4; ++dt)
#pragma unroll
      for (int j = 0; j < 4; ++j)
        oacc[dt][j] *= alpha[j];

    // P -> bf16 -> wave-private LDS (C-layout to A-layout redistribution)
#pragma unroll
    for (int ct = 0; ct < 4; ++ct)
#pragma unroll
      for (int j = 0; j < 4; ++j)
        Pw[(hi * 4 + j) * 72 + ct * 16 + lo] = f2bf(sc[ct][j]);

    asm volatile("s_waitcnt lgkmcnt(0)" ::: "memory");

    // PV: O += P[16x64] * V[64x64]
#pragma unroll
    for (int kb = 0; kb < 2; ++kb) {
      bf16x8 pf = *(const bf16x8*)&Pw[lo * 72 + kb * 32 + hi * 8];
#pragma unroll
      for (int dt = 0; dt < 4; ++dt) {
        bf16x8 vf = *(const bf16x8*)&Vt[(dt * 16 + lo) * 72 + kb * 32 + hi * 8];
        oacc[dt] = MFMA_BF16(pf, vf, oacc[dt], 0, 0, 0);
      }
    }
  }

  // epilogue: O / l, bf16, [b][s][h*64+d] layout for the output GEMM
  const int b = bh >> 4, h = bh & 15;
#pragma unroll
  for (int dt = 0; dt < 4; ++dt)
#pragma unroll
    for (int j = 0; j < 4; ++j) {
      const float v = oacc[dt][j] / lrow[j];
      const int q = qbase + w * 16 + hi * 4 + j;
      const int e = h * 64 + dt * 16 + lo;
      Ob[((size_t)(b * 2048 + q)) * 1024 + e] = f2bf(v);
    }
}

extern "C" void kernel_launch(void* const* d_in, const int* in_sizes, int n_in,
                              void* d_out, int out_size, void* d_ws, size_t ws_size,
                              hipStream_t stream) {
  const float* x  = (const float*)d_in[0];
  const float* wq = (const float*)d_in[1];
  const float* wk = (const float*)d_in[2];
  const float* wv = (const float*)d_in[3];
  const float* wo = (const float*)d_in[4];
  const int* pos  = (const int*)d_in[5];

  char* ws = (char*)d_ws;
  unsigned short* xb = (unsigned short*)(ws);               // 8192x1024 bf16
  unsigned short* wb = (unsigned short*)(ws + 16777216);    // 4x 1024x1024 bf16
  unsigned short* Qb = (unsigned short*)(ws + 25165824);    // [b][h][s][d] bf16
  unsigned short* Kb = (unsigned short*)(ws + 41943040);
  unsigned short* Vb = (unsigned short*)(ws + 58720256);
  unsigned short* Ob = (unsigned short*)(ws + 75497472);    // [b][s][e] bf16
  float2* tab        = (float2*)(ws + 92274688);            // [2048][32] cos/sin

  cast_bf16_k<<<4096, 256, 0, stream>>>(x, xb, 1048576);
  cast_bf16_k<<<512, 256, 0, stream>>>(wq, wb + 0 * 1048576, 131072);
  cast_bf16_k<<<512, 256, 0, stream>>>(wk, wb + 1 * 1048576, 131072);
  cast_bf16_k<<<512, 256, 0, stream>>>(wv, wb + 2 * 1048576, 131072);
  cast_bf16_k<<<512, 256, 0, stream>>>(wo, wb + 3 * 1048576, 131072);
  rope_tab_k<<<256, 256, 0, stream>>>(pos, tab);
  gemm_bt<0><<<dim3(64, 8, 3), 256, 0, stream>>>(xb, wb, Qb, Kb, Vb, nullptr, tab);
  attn_k<<<dim3(32, 64), 256, 0, stream>>>(Qb, Kb, Vb, Ob);
  gemm_bt<1><<<dim3(64, 8, 1), 256, 0, stream>>>(Ob, wb + 3 * 1048576, nullptr,
                                                 nullptr, nullptr, (float*)d_out, tab);
}

// Round 4
// 375.066 us; speedup vs baseline: 1.5508x; 1.5508x over previous
//
#include <hip/hip_runtime.h>
#include <hip/hip_bf16.h>

typedef __attribute__((ext_vector_type(8))) __bf16 bf16x8;
typedef __attribute__((ext_vector_type(4))) float f32x4;
typedef __attribute__((ext_vector_type(16))) float f32x16;
typedef __attribute__((ext_vector_type(4))) unsigned int u32x4;

#define MFMA16 __builtin_amdgcn_mfma_f32_16x16x32_bf16
#define MFMA32 __builtin_amdgcn_mfma_f32_32x32x16_bf16
#define GLOAD_LDS(g, l)                                                      \
  __builtin_amdgcn_global_load_lds(                                          \
      (const __attribute__((address_space(1))) void*)(g),                    \
      (__attribute__((address_space(3))) void*)(l), 16, 0, 0)

static __device__ __forceinline__ unsigned short f2bf(float f) {
  unsigned int u = __builtin_bit_cast(unsigned int, f);
  u += 0x7fffu + ((u >> 16) & 1u);
  return (unsigned short)(u >> 16);
}

// ---------- fp32 -> bf16 cast, 8 elems/thread ----------
__global__ __launch_bounds__(256) void cast_bf16_k(const float* __restrict__ in,
                                                   unsigned short* __restrict__ out,
                                                   int n8) {
  int i = blockIdx.x * 256 + threadIdx.x;
  if (i >= n8) return;
  const float4* p = (const float4*)in + (size_t)i * 2;
  float4 a = p[0], b = p[1];
  ushort4 r0, r1;
  r0.x = f2bf(a.x); r0.y = f2bf(a.y); r0.z = f2bf(a.z); r0.w = f2bf(a.w);
  r1.x = f2bf(b.x); r1.y = f2bf(b.y); r1.z = f2bf(b.z); r1.w = f2bf(b.w);
  ushort4* q = (ushort4*)out + (size_t)i * 2;
  q[0] = r0; q[1] = r1;
}

// ---------- RoPE cos/sin table: [2048][32] float2 ----------
__global__ __launch_bounds__(256) void rope_tab_k(const int* __restrict__ pos,
                                                  float2* __restrict__ tab) {
  int t = blockIdx.x * 256 + threadIdx.x;  // 65536 total
  int s = t >> 5, k = t & 31;
  float p = (float)pos[s];
  float inv = powf(10000.0f, -(float)(2 * k) / 64.0f);
  float ang = p * inv;
  tab[t] = make_float2(cosf(ang), sinf(ang));
}

// ---------- bf16 GEMM: C[M][N] = A[M][K] * B^T, B given as [N][K] ----------
// MODE 0: A=x_bf16 (M=8192), z in {0,1} selects w_{q,k}; epilogue RoPE, Q*=1/8,
//         bf16 scatter to per-head [b][h][s][d].
// MODE 1: A=O_bf16, W=w_o_bf16; fp32 store to Cout (ldc=1024).
// MODE 2: A=w_v (M=1024), W=x_bf16 (N=8192); bf16 store V^T[e][b*S+s] (ldc=8192).
template <int MODE>
__global__ __launch_bounds__(256) void gemm_bt(
    const unsigned short* __restrict__ A, const unsigned short* __restrict__ W,
    unsigned short* __restrict__ Qb, unsigned short* __restrict__ Kb,
    unsigned short* __restrict__ Vb, float* __restrict__ Cout,
    const float2* __restrict__ rtab) {
  __shared__ unsigned short As[128 * 64];
  __shared__ unsigned short Bs[128 * 64];
  const int tid = threadIdx.x;
  const int lane = tid & 63;
  const int w = tid >> 6;          // wave 0..3
  const int wr = w >> 1, wc = w & 1;
  const int hi = lane >> 4, lo = lane & 15;
  const int m0 = blockIdx.x * 128;
  const int n0 = blockIdx.y * 128;
  const int z = blockIdx.z;
  const unsigned short* Bmat = W + (size_t)z * 1024 * 1024;

  const int sr = lane >> 3;        // staging row within 8-row chunk
  const int sc8 = (lane & 7) * 8;  // staging col (elements)

  f32x4 acc[4][4] = {};

  for (int kt = 0; kt < 16; ++kt) {
    const int kofs = kt * 64;
#pragma unroll
    for (int c = 0; c < 4; ++c) {
      const int rowA = c * 32 + w * 8;
      const unsigned short* ga = A + (size_t)(m0 + rowA + sr) * 1024 + kofs + sc8;
      GLOAD_LDS(ga, &As[rowA * 64]);
      const unsigned short* gb = Bmat + (size_t)(n0 + rowA + sr) * 1024 + kofs + sc8;
      GLOAD_LDS(gb, &Bs[rowA * 64]);
    }
    __syncthreads();
#pragma unroll
    for (int kb = 0; kb < 2; ++kb) {
      bf16x8 af[4], bfr[4];
#pragma unroll
      for (int mt = 0; mt < 4; ++mt)
        af[mt] = *(const bf16x8*)&As[(wr * 64 + mt * 16 + lo) * 64 + kb * 32 + hi * 8];
#pragma unroll
      for (int nt = 0; nt < 4; ++nt)
        bfr[nt] = *(const bf16x8*)&Bs[(wc * 64 + nt * 16 + lo) * 64 + kb * 32 + hi * 8];
#pragma unroll
      for (int mt = 0; mt < 4; ++mt)
#pragma unroll
        for (int nt = 0; nt < 4; ++nt)
          acc[mt][nt] = MFMA16(af[mt], bfr[nt], acc[mt][nt], 0, 0, 0);
    }
    __syncthreads();
  }

  // Epilogue. C/D layout: row = (lane>>4)*4 + j, col = lane&15 (verified m89/m91).
#pragma unroll
  for (int mt = 0; mt < 4; ++mt) {
#pragma unroll
    for (int nt = 0; nt < 4; ++nt) {
      const int c = n0 + wc * 64 + nt * 16 + lo;
#pragma unroll
      for (int j = 0; j < 4; ++j) {
        const int r = m0 + wr * 64 + mt * 16 + hi * 4 + j;
        float v = acc[mt][nt][j];
        if constexpr (MODE == 1) {
          Cout[(size_t)r * 1024 + c] = v;
        } else if constexpr (MODE == 2) {
          Vb[(size_t)r * 8192 + c] = f2bf(v);  // V^T[e][b*S+s]
        } else {
          const float other = __shfl_xor(v, 1);  // partner column (c^1)
          const int b = r >> 11, s = r & 2047;
          const int h = c >> 6, dd = c & 63;
          float2 cs = rtab[s * 32 + (dd >> 1)];
          float outv = (dd & 1) ? (cs.y * other + cs.x * v)
                                : (cs.x * v - cs.y * other);
          if (z == 0) outv *= 0.125f;  // fold softmax scale into Q (exact pow2)
          unsigned short* dst = (z == 0) ? Qb : Kb;
          dst[((size_t)(b * 16 + h) * 2048 + s) * 64 + dd] = f2bf(outv);
        }
      }
    }
  }
}

// ---------- causal flash attention, swapped-operand 32x32 structure ----------
// Block: 256 thr = 4 waves, each wave owns 32 q-rows (QBLK=128). KV tile = 64.
// S^T = K.Q^T  (lane&31 = q, regs = k)  -> softmax fully lane-local (+1 shfl)
// O^T = V^T.P^T (lane&31 = q, regs = d) -> rescale lane-local
// K and V^T staged in LDS [64][64] u16 with chunk-XOR swizzle (chunk^=row&7),
// sources pre-swizzled for global_load_lds (involution, rule #21).
__global__ __launch_bounds__(256) void attn_k(const unsigned short* __restrict__ Qb,
                                              const unsigned short* __restrict__ Kb,
                                              const unsigned short* __restrict__ VtG,
                                              unsigned short* __restrict__ Ob) {
  __shared__ unsigned short Kl[64 * 64];
  __shared__ unsigned short Vl[64 * 64];
  const int tid = threadIdx.x;
  const int lane = tid & 63;
  const int w = tid >> 6;
  const int q32 = lane & 31;
  const int hi = lane >> 5;
  const int l7 = lane & 7;
  const int qt = (int)gridDim.x - 1 - (int)blockIdx.x;  // heavy blocks first
  const int bh = blockIdx.y;
  const int b = bh >> 4, h = bh & 15;
  const int qw = qt * 128 + w * 32;   // wave's q base
  const int qpos = qw + q32;          // this lane's q row
  const unsigned short* Qp = Qb + (size_t)bh * 2048 * 64;
  const unsigned short* Kp = Kb + (size_t)bh * 2048 * 64;
  const unsigned short* Vg = VtG + (size_t)h * 64 * 8192 + b * 2048;

  // Q fragments (B-operand: col=lane&31=q, k = hi*8+e within d-slice)
  bf16x8 qf[4];
#pragma unroll
  for (int ds = 0; ds < 4; ++ds)
    qf[ds] = *(const bf16x8*)&Qp[(size_t)qpos * 64 + ds * 16 + hi * 8];

  f32x16 oa0 = {}, oa1 = {};          // O^T acc, d-blocks 0/1 (regs = d, lane = q)
  float mrow = -1e30f, lsum = 0.0f;

  const int srow = lane >> 3;         // 0..7: row within 8-row staging chunk
  const int csrc = l7 ^ srow;         // pre-swizzled global chunk (involution)
  const int ntiles = 2 * qt + 2;

  for (int kt = 0; kt < ntiles; ++kt) {
    __syncthreads();                  // prior tile's LDS reads complete
#pragma unroll
    for (int i = 0; i < 2; ++i) {
      const int r = w * 16 + i * 8 + srow;
      GLOAD_LDS(Kp + ((size_t)(kt * 64 + r)) * 64 + csrc * 8,
                &Kl[(w * 16 + i * 8) * 64]);
      GLOAD_LDS(Vg + (size_t)r * 8192 + kt * 64 + csrc * 8,
                &Vl[(w * 16 + i * 8) * 64]);
    }
    __syncthreads();                  // implicit vmcnt(0) drain -> tiles ready

    // QK^T swapped: S[kpos][q], kpos blocks 0-31 (s0) and 32-63 (s1)
    f32x16 s0 = {}, s1 = {};
#pragma unroll
    for (int ds = 0; ds < 4; ++ds) {
      const int cc = ((ds * 2 + hi) ^ l7) * 8;
      bf16x8 k0 = *(const bf16x8*)&Kl[q32 * 64 + cc];
      bf16x8 k1 = *(const bf16x8*)&Kl[(32 + q32) * 64 + cc];
      s0 = MFMA32(k0, qf[ds], s0, 0, 0, 0);
      s1 = MFMA32(k1, qf[ds], s1, 0, 0, 0);
    }

    if (kt * 64 + 63 > qw) {          // tile may contain kpos > qpos for this wave
#pragma unroll
      for (int r = 0; r < 16; ++r) {
        const int krel = (r & 3) + 8 * (r >> 2) + 4 * hi;
        if (kt * 64 + krel > qpos) s0[r] = -1e30f;
        if (kt * 64 + 32 + krel > qpos) s1[r] = -1e30f;
      }
    }

    // online softmax: everything lane-local except one ^32 exchange
    float tmax = -1e30f;
#pragma unroll
    for (int r = 0; r < 16; ++r) tmax = fmaxf(tmax, fmaxf(s0[r], s1[r]));
    tmax = fmaxf(tmax, __shfl_xor(tmax, 32));
    const float mnew = fmaxf(mrow, tmax);
    const float alpha = __expf(mrow - mnew);
    mrow = mnew;
    float rsum = 0.0f;
#pragma unroll
    for (int r = 0; r < 16; ++r) {
      s0[r] = __expf(s0[r] - mnew);
      s1[r] = __expf(s1[r] - mnew);
      rsum += s0[r] + s1[r];
    }
    rsum += __shfl_xor(rsum, 32);
    lsum = lsum * alpha + rsum;
#pragma unroll
    for (int r = 0; r < 16; ++r) { oa0[r] *= alpha; oa1[r] *= alpha; }

    // P^T fragments: pack pairs to bf16, exchange reg-groups across lane^32.
    // Own regs cover k' {0-3,8-11,16-19,24-27}+4*hi; partner holds the rest.
    unsigned int A0[8], A1[8], B0[8], B1[8];
#pragma unroll
    for (int i = 0; i < 8; ++i) {
      A0[i] = ((unsigned int)f2bf(s0[2 * i + 1]) << 16) | f2bf(s0[2 * i]);
      A1[i] = ((unsigned int)f2bf(s1[2 * i + 1]) << 16) | f2bf(s1[2 * i]);
    }
#pragma unroll
    for (int i = 0; i < 8; ++i) {
      B0[i] = (unsigned int)__shfl_xor((int)A0[i], 32);
      B1[i] = (unsigned int)__shfl_xor((int)A1[i], 32);
    }
    u32x4 pw0, pw1, pw2, pw3;  // P^T B-frags for k-slices 0..3 (words w0..w3)
    if (hi) {
      pw0 = (u32x4){B0[2], B0[3], A0[2], A0[3]};
      pw1 = (u32x4){B0[6], B0[7], A0[6], A0[7]};
      pw2 = (u32x4){B1[2], B1[3], A1[2], A1[3]};
      pw3 = (u32x4){B1[6], B1[7], A1[6], A1[7]};
    } else {
      pw0 = (u32x4){A0[0], A0[1], B0[0], B0[1]};
      pw1 = (u32x4){A0[4], A0[5], B0[4], B0[5]};
      pw2 = (u32x4){A1[0], A1[1], B1[0], B1[1]};
      pw3 = (u32x4){A1[4], A1[5], B1[4], B1[5]};
    }

    // PV transposed: O^T[d][q] += V^T[d][k-slice] . P^T[k-slice][q]
#pragma unroll
    for (int ks = 0; ks < 4; ++ks) {
      const int cc = ((ks * 2 + hi) ^ l7) * 8;
      bf16x8 v0 = *(const bf16x8*)&Vl[q32 * 64 + cc];
      bf16x8 v1 = *(const bf16x8*)&Vl[(32 + q32) * 64 + cc];
      const u32x4 pwk = (ks == 0) ? pw0 : (ks == 1) ? pw1 : (ks == 2) ? pw2 : pw3;
      bf16x8 pb = __builtin_bit_cast(bf16x8, pwk);
      oa0 = MFMA32(v0, pb, oa0, 0, 0, 0);
      oa1 = MFMA32(v1, pb, oa1, 0, 0, 0);
    }
  }

  // epilogue: O = (O^T)/l, write [b][s][h*64+d]; regs 4g..4g+3 -> d=8g+4hi+0..3
  const float invl = 1.0f / lsum;
  unsigned short* orow = Ob + ((size_t)(b * 2048 + qpos)) * 1024 + h * 64;
#pragma unroll
  for (int g = 0; g < 4; ++g) {
    ushort4 o0, o1;
    o0.x = f2bf(oa0[4 * g + 0] * invl); o0.y = f2bf(oa0[4 * g + 1] * invl);
    o0.z = f2bf(oa0[4 * g + 2] * invl); o0.w = f2bf(oa0[4 * g + 3] * invl);
    o1.x = f2bf(oa1[4 * g + 0] * invl); o1.y = f2bf(oa1[4 * g + 1] * invl);
    o1.z = f2bf(oa1[4 * g + 2] * invl); o1.w = f2bf(oa1[4 * g + 3] * invl);
    *(ushort4*)&orow[g * 8 + hi * 4] = o0;
    *(ushort4*)&orow[32 + g * 8 + hi * 4] = o1;
  }
}

extern "C" void kernel_launch(void* const* d_in, const int* in_sizes, int n_in,
                              void* d_out, int out_size, void* d_ws, size_t ws_size,
                              hipStream_t stream) {
  const float* x  = (const float*)d_in[0];
  const float* wq = (const float*)d_in[1];
  const float* wk = (const float*)d_in[2];
  const float* wv = (const float*)d_in[3];
  const float* wo = (const float*)d_in[4];
  const int* pos  = (const int*)d_in[5];

  char* ws = (char*)d_ws;
  unsigned short* xb  = (unsigned short*)(ws);               // 8192x1024 bf16
  unsigned short* wb  = (unsigned short*)(ws + 16777216);    // 4x 1024x1024 bf16
  unsigned short* Qb  = (unsigned short*)(ws + 25165824);    // [b][h][s][d] bf16
  unsigned short* Kb  = (unsigned short*)(ws + 41943040);    // [b][h][s][d] bf16
  unsigned short* Vt  = (unsigned short*)(ws + 58720256);    // V^T [e][b*S+s] bf16
  unsigned short* Ob  = (unsigned short*)(ws + 75497472);    // [b][s][e] bf16
  float2* tab         = (float2*)(ws + 92274688);            // [2048][32] cos/sin

  cast_bf16_k<<<4096, 256, 0, stream>>>(x, xb, 1048576);
  cast_bf16_k<<<512, 256, 0, stream>>>(wq, wb + 0 * 1048576, 131072);
  cast_bf16_k<<<512, 256, 0, stream>>>(wk, wb + 1 * 1048576, 131072);
  cast_bf16_k<<<512, 256, 0, stream>>>(wv, wb + 2 * 1048576, 131072);
  cast_bf16_k<<<512, 256, 0, stream>>>(wo, wb + 3 * 1048576, 131072);
  rope_tab_k<<<256, 256, 0, stream>>>(pos, tab);
  gemm_bt<0><<<dim3(64, 8, 2), 256, 0, stream>>>(xb, wb, Qb, Kb, nullptr, nullptr, tab);
  gemm_bt<2><<<dim3(8, 64, 1), 256, 0, stream>>>(wb + 2 * 1048576, xb, nullptr,
                                                 nullptr, Vt, nullptr, tab);
  attn_k<<<dim3(16, 64), 256, 0, stream>>>(Qb, Kb, Vt, Ob);
  gemm_bt<1><<<dim3(64, 8, 1), 256, 0, stream>>>(Ob, wb + 3 * 1048576, nullptr,
                                                 nullptr, nullptr, (float*)d_out, tab);
}

// Round 5
// 369.171 us; speedup vs baseline: 1.5756x; 1.0160x over previous
//
#include <hip/hip_runtime.h>
#include <hip/hip_bf16.h>

typedef __attribute__((ext_vector_type(8))) __bf16 bf16x8;
typedef __attribute__((ext_vector_type(4))) float f32x4;
typedef __attribute__((ext_vector_type(16))) float f32x16;
typedef __attribute__((ext_vector_type(4))) unsigned int u32x4;

#define MFMA16 __builtin_amdgcn_mfma_f32_16x16x32_bf16
#define MFMA32 __builtin_amdgcn_mfma_f32_32x32x16_bf16
#define GLOAD_LDS(g, l)                                                      \
  __builtin_amdgcn_global_load_lds(                                          \
      (const __attribute__((address_space(1))) void*)(g),                    \
      (__attribute__((address_space(3))) void*)(l), 16, 0, 0)

static __device__ __forceinline__ unsigned short f2bf(float f) {
  unsigned int u = __builtin_bit_cast(unsigned int, f);
  u += 0x7fffu + ((u >> 16) & 1u);
  return (unsigned short)(u >> 16);
}

// ---------- fp32 -> bf16 cast, 8 elems/thread ----------
__global__ __launch_bounds__(256) void cast_bf16_k(const float* __restrict__ in,
                                                   unsigned short* __restrict__ out,
                                                   int n8) {
  int i = blockIdx.x * 256 + threadIdx.x;
  if (i >= n8) return;
  const float4* p = (const float4*)in + (size_t)i * 2;
  float4 a = p[0], b = p[1];
  ushort4 r0, r1;
  r0.x = f2bf(a.x); r0.y = f2bf(a.y); r0.z = f2bf(a.z); r0.w = f2bf(a.w);
  r1.x = f2bf(b.x); r1.y = f2bf(b.y); r1.z = f2bf(b.z); r1.w = f2bf(b.w);
  ushort4* q = (ushort4*)out + (size_t)i * 2;
  q[0] = r0; q[1] = r1;
}

// ---------- RoPE cos/sin table: [2048][32] float2 ----------
__global__ __launch_bounds__(256) void rope_tab_k(const int* __restrict__ pos,
                                                  float2* __restrict__ tab) {
  int t = blockIdx.x * 256 + threadIdx.x;  // 65536 total
  int s = t >> 5, k = t & 31;
  float p = (float)pos[s];
  float inv = powf(10000.0f, -(float)(2 * k) / 64.0f);
  float ang = p * inv;
  tab[t] = make_float2(cosf(ang), sinf(ang));
}

// ---------- bf16 GEMM: C[M][N] = A[M][K] * B^T, B given as [N][K] ----------
// MODE 0: A=x_bf16 (M=8192), z in {0,1} selects w_{q,k}; epilogue RoPE,
//         Q *= 0.125*log2(e) (exp2 softmax domain), bf16 scatter to [b][h][s][d].
// MODE 1: A=O_bf16, W=w_o_bf16; fp32 store to Cout (ldc=1024).
// MODE 2: A=w_v (M=1024), W=x_bf16 (N=8192); bf16 store V^T[e][b*S+s] (ldc=8192).
template <int MODE>
__global__ __launch_bounds__(256) void gemm_bt(
    const unsigned short* __restrict__ A, const unsigned short* __restrict__ W,
    unsigned short* __restrict__ Qb, unsigned short* __restrict__ Kb,
    unsigned short* __restrict__ Vb, float* __restrict__ Cout,
    const float2* __restrict__ rtab) {
  __shared__ unsigned short As[128 * 64];
  __shared__ unsigned short Bs[128 * 64];
  const int tid = threadIdx.x;
  const int lane = tid & 63;
  const int w = tid >> 6;          // wave 0..3
  const int wr = w >> 1, wc = w & 1;
  const int hi = lane >> 4, lo = lane & 15;
  const int m0 = blockIdx.x * 128;
  const int n0 = blockIdx.y * 128;
  const int z = blockIdx.z;
  const unsigned short* Bmat = W + (size_t)z * 1024 * 1024;

  const int sr = lane >> 3;        // staging row within 8-row chunk
  const int sc8 = (lane & 7) * 8;  // staging col (elements)

  f32x4 acc[4][4] = {};

  for (int kt = 0; kt < 16; ++kt) {
    const int kofs = kt * 64;
#pragma unroll
    for (int c = 0; c < 4; ++c) {
      const int rowA = c * 32 + w * 8;
      const unsigned short* ga = A + (size_t)(m0 + rowA + sr) * 1024 + kofs + sc8;
      GLOAD_LDS(ga, &As[rowA * 64]);
      const unsigned short* gb = Bmat + (size_t)(n0 + rowA + sr) * 1024 + kofs + sc8;
      GLOAD_LDS(gb, &Bs[rowA * 64]);
    }
    __syncthreads();
#pragma unroll
    for (int kb = 0; kb < 2; ++kb) {
      bf16x8 af[4], bfr[4];
#pragma unroll
      for (int mt = 0; mt < 4; ++mt)
        af[mt] = *(const bf16x8*)&As[(wr * 64 + mt * 16 + lo) * 64 + kb * 32 + hi * 8];
#pragma unroll
      for (int nt = 0; nt < 4; ++nt)
        bfr[nt] = *(const bf16x8*)&Bs[(wc * 64 + nt * 16 + lo) * 64 + kb * 32 + hi * 8];
#pragma unroll
      for (int mt = 0; mt < 4; ++mt)
#pragma unroll
        for (int nt = 0; nt < 4; ++nt)
          acc[mt][nt] = MFMA16(af[mt], bfr[nt], acc[mt][nt], 0, 0, 0);
    }
    __syncthreads();
  }

  // Epilogue. C/D layout: row = (lane>>4)*4 + j, col = lane&15 (verified m89/m91).
#pragma unroll
  for (int mt = 0; mt < 4; ++mt) {
#pragma unroll
    for (int nt = 0; nt < 4; ++nt) {
      const int c = n0 + wc * 64 + nt * 16 + lo;
#pragma unroll
      for (int j = 0; j < 4; ++j) {
        const int r = m0 + wr * 64 + mt * 16 + hi * 4 + j;
        float v = acc[mt][nt][j];
        if constexpr (MODE == 1) {
          Cout[(size_t)r * 1024 + c] = v;
        } else if constexpr (MODE == 2) {
          Vb[(size_t)r * 8192 + c] = f2bf(v);  // V^T[e][b*S+s]
        } else {
          const float other = __shfl_xor(v, 1);  // partner column (c^1)
          const int b = r >> 11, s = r & 2047;
          const int h = c >> 6, dd = c & 63;
          float2 cs = rtab[s * 32 + (dd >> 1)];
          float outv = (dd & 1) ? (cs.y * other + cs.x * v)
                                : (cs.x * v - cs.y * other);
          // fold softmax scale AND log2(e) into Q: exp2-domain softmax
          if (z == 0) outv *= 0.18033688012f;  // 0.125 * log2(e)
          unsigned short* dst = (z == 0) ? Qb : Kb;
          dst[((size_t)(b * 16 + h) * 2048 + s) * 64 + dd] = f2bf(outv);
        }
      }
    }
  }
}

// ---------- causal flash attention, swapped-operand 32x32, pipelined ----------
// Flat grid 1024. XCD-chunked swizzle: bh = (lin&7)*8 + (lin>>7) puts all 16
// qt-blocks of one (b,h) on one XCD (K+V = 512KB << 4MB L2); heavy-first.
// Double-buffered LDS staging, ONE raw barrier per tile: loads for tile t+1
// fly during tile-t compute (T3-minimum); vmcnt(0) drained at iter end.
__global__ __launch_bounds__(256) void attn_k(const unsigned short* __restrict__ Qb,
                                              const unsigned short* __restrict__ Kb,
                                              const unsigned short* __restrict__ VtG,
                                              unsigned short* __restrict__ Ob) {
  __shared__ unsigned short Kl[2][64 * 64];
  __shared__ unsigned short Vl[2][64 * 64];
  const int tid = threadIdx.x;
  const int lane = tid & 63;
  const int w = tid >> 6;
  const int q32 = lane & 31;
  const int hi = lane >> 5;
  const int l7 = lane & 7;
  const int lin = blockIdx.x;           // 0..1023
  const int slot = lin >> 3;            // 0..127 within XCD
  const int bh = (lin & 7) * 8 + (slot >> 4);
  const int qt = 15 - (slot & 15);      // heavy-first within each bh group
  const int b = bh >> 4, h = bh & 15;
  const int qw = qt * 128 + w * 32;     // wave's q base
  const int qpos = qw + q32;            // this lane's q row
  const unsigned short* Qp = Qb + (size_t)bh * 2048 * 64;
  const unsigned short* Kp = Kb + (size_t)bh * 2048 * 64;
  const unsigned short* Vg = VtG + (size_t)h * 64 * 8192 + b * 2048;

  // Q fragments (B-operand: col=lane&31=q, k = hi*8+e within d-slice)
  bf16x8 qf[4];
#pragma unroll
  for (int ds = 0; ds < 4; ++ds)
    qf[ds] = *(const bf16x8*)&Qp[(size_t)qpos * 64 + ds * 16 + hi * 8];

  f32x16 oa0 = {}, oa1 = {};            // O^T acc, d-blocks 0/1 (regs=d, lane=q)
  float mrow = -1e30f, lsum = 0.0f;

  const int srow = lane >> 3;           // 0..7: row within 8-row staging chunk
  const int csrc = l7 ^ srow;           // pre-swizzled global chunk (involution)
  const int ntiles = 2 * qt + 2;

  // stage one 64x64 K tile + 64x64 V^T tile into buffer `buf`
  auto stage = [&](int kt, int buf) {
#pragma unroll
    for (int i = 0; i < 2; ++i) {
      const int r = w * 16 + i * 8 + srow;
      GLOAD_LDS(Kp + ((size_t)(kt * 64 + r)) * 64 + csrc * 8,
                &Kl[buf][(w * 16 + i * 8) * 64]);
      GLOAD_LDS(Vg + (size_t)r * 8192 + kt * 64 + csrc * 8,
                &Vl[buf][(w * 16 + i * 8) * 64]);
    }
  };

  stage(0, 0);
  asm volatile("s_waitcnt vmcnt(0)" ::: "memory");
  __builtin_amdgcn_s_barrier();
  asm volatile("" ::: "memory");

  int cur = 0;
  for (int kt = 0; kt < ntiles; ++kt) {
    if (kt + 1 < ntiles) stage(kt + 1, cur ^ 1);  // prefetch overlaps compute
    const unsigned short* Kc = &Kl[cur][0];
    const unsigned short* Vc = &Vl[cur][0];

    // QK^T swapped: S[kpos][q], kpos blocks 0-31 (s0) and 32-63 (s1)
    f32x16 s0 = {}, s1 = {};
#pragma unroll
    for (int ds = 0; ds < 4; ++ds) {
      const int cc = ((ds * 2 + hi) ^ l7) * 8;
      bf16x8 k0 = *(const bf16x8*)&Kc[q32 * 64 + cc];
      bf16x8 k1 = *(const bf16x8*)&Kc[(32 + q32) * 64 + cc];
      s0 = MFMA32(k0, qf[ds], s0, 0, 0, 0);
      s1 = MFMA32(k1, qf[ds], s1, 0, 0, 0);
    }

    if (kt * 64 + 63 > qw) {            // tile may contain kpos > qpos
#pragma unroll
      for (int r = 0; r < 16; ++r) {
        const int krel = (r & 3) + 8 * (r >> 2) + 4 * hi;
        if (kt * 64 + krel > qpos) s0[r] = -1e30f;
        if (kt * 64 + 32 + krel > qpos) s1[r] = -1e30f;
      }
    }

    // online softmax in exp2 domain (scores pre-scaled by 0.125*log2e via Q)
    float tmax = -1e30f;
#pragma unroll
    for (int r = 0; r < 16; ++r) tmax = fmaxf(tmax, fmaxf(s0[r], s1[r]));
    tmax = fmaxf(tmax, __shfl_xor(tmax, 32));
    const float mnew = fmaxf(mrow, tmax);
    const float alpha = exp2f(mrow - mnew);
    mrow = mnew;
    float rsum = 0.0f;
#pragma unroll
    for (int r = 0; r < 16; ++r) {
      s0[r] = exp2f(s0[r] - mnew);
      s1[r] = exp2f(s1[r] - mnew);
      rsum += s0[r] + s1[r];
    }
    rsum += __shfl_xor(rsum, 32);
    lsum = lsum * alpha + rsum;
#pragma unroll
    for (int r = 0; r < 16; ++r) { oa0[r] *= alpha; oa1[r] *= alpha; }

    // P^T fragments: pack pairs to bf16, exchange reg-groups across lane^32.
    unsigned int A0[8], A1[8], B0[8], B1[8];
#pragma unroll
    for (int i = 0; i < 8; ++i) {
      A0[i] = ((unsigned int)f2bf(s0[2 * i + 1]) << 16) | f2bf(s0[2 * i]);
      A1[i] = ((unsigned int)f2bf(s1[2 * i + 1]) << 16) | f2bf(s1[2 * i]);
    }
#pragma unroll
    for (int i = 0; i < 8; ++i) {
      B0[i] = (unsigned int)__shfl_xor((int)A0[i], 32);
      B1[i] = (unsigned int)__shfl_xor((int)A1[i], 32);
    }
    u32x4 pw0, pw1, pw2, pw3;  // P^T B-frags for k-slices 0..3
    if (hi) {
      pw0 = (u32x4){B0[2], B0[3], A0[2], A0[3]};
      pw1 = (u32x4){B0[6], B0[7], A0[6], A0[7]};
      pw2 = (u32x4){B1[2], B1[3], A1[2], A1[3]};
      pw3 = (u32x4){B1[6], B1[7], A1[6], A1[7]};
    } else {
      pw0 = (u32x4){A0[0], A0[1], B0[0], B0[1]};
      pw1 = (u32x4){A0[4], A0[5], B0[4], B0[5]};
      pw2 = (u32x4){A1[0], A1[1], B1[0], B1[1]};
      pw3 = (u32x4){A1[4], A1[5], B1[4], B1[5]};
    }

    // PV transposed: O^T[d][q] += V^T[d][k-slice] . P^T[k-slice][q]
#pragma unroll
    for (int ks = 0; ks < 4; ++ks) {
      const int cc = ((ks * 2 + hi) ^ l7) * 8;
      bf16x8 v0 = *(const bf16x8*)&Vc[q32 * 64 + cc];
      bf16x8 v1 = *(const bf16x8*)&Vc[(32 + q32) * 64 + cc];
      const u32x4 pwk = (ks == 0) ? pw0 : (ks == 1) ? pw1 : (ks == 2) ? pw2 : pw3;
      bf16x8 pb = __builtin_bit_cast(bf16x8, pwk);
      oa0 = MFMA32(v0, pb, oa0, 0, 0, 0);
      oa1 = MFMA32(v1, pb, oa1, 0, 0, 0);
    }

    // drain next-tile loads (had full compute to finish) + join all waves
    asm volatile("s_waitcnt vmcnt(0)" ::: "memory");
    __builtin_amdgcn_s_barrier();
    asm volatile("" ::: "memory");
    cur ^= 1;
  }

  // epilogue: O = (O^T)/l, write [b][s][h*64+d]; regs 4g..4g+3 -> d=8g+4hi+0..3
  const float invl = 1.0f / lsum;
  unsigned short* orow = Ob + ((size_t)(b * 2048 + qpos)) * 1024 + h * 64;
#pragma unroll
  for (int g = 0; g < 4; ++g) {
    ushort4 o0, o1;
    o0.x = f2bf(oa0[4 * g + 0] * invl); o0.y = f2bf(oa0[4 * g + 1] * invl);
    o0.z = f2bf(oa0[4 * g + 2] * invl); o0.w = f2bf(oa0[4 * g + 3] * invl);
    o1.x = f2bf(oa1[4 * g + 0] * invl); o1.y = f2bf(oa1[4 * g + 1] * invl);
    o1.z = f2bf(oa1[4 * g + 2] * invl); o1.w = f2bf(oa1[4 * g + 3] * invl);
    *(ushort4*)&orow[g * 8 + hi * 4] = o0;
    *(ushort4*)&orow[32 + g * 8 + hi * 4] = o1;
  }
}

extern "C" void kernel_launch(void* const* d_in, const int* in_sizes, int n_in,
                              void* d_out, int out_size, void* d_ws, size_t ws_size,
                              hipStream_t stream) {
  const float* x  = (const float*)d_in[0];
  const float* wq = (const float*)d_in[1];
  const float* wk = (const float*)d_in[2];
  const float* wv = (const float*)d_in[3];
  const float* wo = (const float*)d_in[4];
  const int* pos  = (const int*)d_in[5];

  char* ws = (char*)d_ws;
  unsigned short* xb  = (unsigned short*)(ws);               // 8192x1024 bf16
  unsigned short* wb  = (unsigned short*)(ws + 16777216);    // 4x 1024x1024 bf16
  unsigned short* Qb  = (unsigned short*)(ws + 25165824);    // [b][h][s][d] bf16
  unsigned short* Kb  = (unsigned short*)(ws + 41943040);    // [b][h][s][d] bf16
  unsigned short* Vt  = (unsigned short*)(ws + 58720256);    // V^T [e][b*S+s] bf16
  unsigned short* Ob  = (unsigned short*)(ws + 75497472);    // [b][s][e] bf16
  float2* tab         = (float2*)(ws + 92274688);            // [2048][32] cos/sin

  cast_bf16_k<<<4096, 256, 0, stream>>>(x, xb, 1048576);
  cast_bf16_k<<<512, 256, 0, stream>>>(wq, wb + 0 * 1048576, 131072);
  cast_bf16_k<<<512, 256, 0, stream>>>(wk, wb + 1 * 1048576, 131072);
  cast_bf16_k<<<512, 256, 0, stream>>>(wv, wb + 2 * 1048576, 131072);
  cast_bf16_k<<<512, 256, 0, stream>>>(wo, wb + 3 * 1048576, 131072);
  rope_tab_k<<<256, 256, 0, stream>>>(pos, tab);
  gemm_bt<0><<<dim3(64, 8, 2), 256, 0, stream>>>(xb, wb, Qb, Kb, nullptr, nullptr, tab);
  gemm_bt<2><<<dim3(8, 64, 1), 256, 0, stream>>>(wb + 2 * 1048576, xb, nullptr,
                                                 nullptr, Vt, nullptr, tab);
  attn_k<<<dim3(1024), 256, 0, stream>>>(Qb, Kb, Vt, Ob);
  gemm_bt<1><<<dim3(64, 8, 1), 256, 0, stream>>>(Ob, wb + 3 * 1048576, nullptr,
                                                 nullptr, nullptr, (float*)d_out, tab);
}

// Round 9
// 305.736 us; speedup vs baseline: 1.9025x; 1.2075x over previous
//
#include <hip/hip_runtime.h>
#include <hip/hip_bf16.h>

typedef __attribute__((ext_vector_type(8))) __bf16 bf16x8;
typedef __attribute__((ext_vector_type(2))) __bf16 bf16x2;
typedef __attribute__((ext_vector_type(2))) float f32x2;
typedef __attribute__((ext_vector_type(4))) float f32x4;
typedef __attribute__((ext_vector_type(16))) float f32x16;
typedef __attribute__((ext_vector_type(4))) unsigned int u32x4;
typedef __attribute__((ext_vector_type(2))) int i32x2;

#define MFMA16 __builtin_amdgcn_mfma_f32_16x16x32_bf16
#define MFMA32 __builtin_amdgcn_mfma_f32_32x32x16_bf16
#define GLOAD_LDS(g, l)                                                      \
  __builtin_amdgcn_global_load_lds(                                          \
      (const __attribute__((address_space(1))) void*)(g),                    \
      (__attribute__((address_space(3))) void*)(l), 16, 0, 0)

static __device__ __forceinline__ unsigned short f2bf(float f) {
  return __builtin_bit_cast(unsigned short, (__bf16)f);  // RNE hw cvt
}
static __device__ __forceinline__ unsigned int cvt2(float a, float b) {
  f32x2 t = {a, b};
  return __builtin_bit_cast(unsigned int, __builtin_convertvector(t, bf16x2));
}

// ---------- fp32 -> bf16 cast, 8 elems/thread ----------
__global__ __launch_bounds__(256) void cast_bf16_k(const float* __restrict__ in,
                                                   unsigned short* __restrict__ out,
                                                   int n8) {
  int i = blockIdx.x * 256 + threadIdx.x;
  if (i >= n8) return;
  const float4* p = (const float4*)in + (size_t)i * 2;
  float4 a = p[0], b = p[1];
  uint4 r;
  r.x = cvt2(a.x, a.y); r.y = cvt2(a.z, a.w);
  r.z = cvt2(b.x, b.y); r.w = cvt2(b.z, b.w);
  *((uint4*)out + i) = r;
}

// ---------- RoPE cos/sin table: [2048][32] float2 ----------
__global__ __launch_bounds__(256) void rope_tab_k(const int* __restrict__ pos,
                                                  float2* __restrict__ tab) {
  int t = blockIdx.x * 256 + threadIdx.x;  // 65536 total
  int s = t >> 5, k = t & 31;
  float p = (float)pos[s];
  float inv = powf(10000.0f, -(float)(2 * k) / 64.0f);
  float ang = p * inv;
  tab[t] = make_float2(cosf(ang), sinf(ang));
}

// ---------- bf16 GEMM: C[M][N] = A[M][K] * B^T, B given as [N][K] ----------
// MODE 0: A=x_bf16 (M=8192), z in {0,1} selects w_{q,k}; epilogue RoPE,
//         Q *= 0.125*log2(e) (exp2 softmax domain), bf16 scatter to [b][h][s][d].
// MODE 1: A=O_bf16, W=w_o_bf16; fp32 store to Cout (ldc=1024).
// MODE 2: A=w_v (M=1024), W=x_bf16 (N=8192); bf16 store V^T[e][b*S+s] (ldc=8192).
template <int MODE>
__global__ __launch_bounds__(256) void gemm_bt(
    const unsigned short* __restrict__ A, const unsigned short* __restrict__ W,
    unsigned short* __restrict__ Qb, unsigned short* __restrict__ Kb,
    unsigned short* __restrict__ Vb, float* __restrict__ Cout,
    const float2* __restrict__ rtab) {
  __shared__ unsigned short As[128 * 64];
  __shared__ unsigned short Bs[128 * 64];
  const int tid = threadIdx.x;
  const int lane = tid & 63;
  const int w = tid >> 6;          // wave 0..3
  const int wr = w >> 1, wc = w & 1;
  const int hi = lane >> 4, lo = lane & 15;
  const int m0 = blockIdx.x * 128;
  const int n0 = blockIdx.y * 128;
  const int z = blockIdx.z;
  const unsigned short* Bmat = W + (size_t)z * 1024 * 1024;

  const int sr = lane >> 3;        // staging row within 8-row chunk
  const int sc8 = (lane & 7) * 8;  // staging col (elements)

  f32x4 acc[4][4] = {};

  for (int kt = 0; kt < 16; ++kt) {
    const int kofs = kt * 64;
#pragma unroll
    for (int c = 0; c < 4; ++c) {
      const int rowA = c * 32 + w * 8;
      const unsigned short* ga = A + (size_t)(m0 + rowA + sr) * 1024 + kofs + sc8;
      GLOAD_LDS(ga, &As[rowA * 64]);
      const unsigned short* gb = Bmat + (size_t)(n0 + rowA + sr) * 1024 + kofs + sc8;
      GLOAD_LDS(gb, &Bs[rowA * 64]);
    }
    __syncthreads();
#pragma unroll
    for (int kb = 0; kb < 2; ++kb) {
      bf16x8 af[4], bfr[4];
#pragma unroll
      for (int mt = 0; mt < 4; ++mt)
        af[mt] = *(const bf16x8*)&As[(wr * 64 + mt * 16 + lo) * 64 + kb * 32 + hi * 8];
#pragma unroll
      for (int nt = 0; nt < 4; ++nt)
        bfr[nt] = *(const bf16x8*)&Bs[(wc * 64 + nt * 16 + lo) * 64 + kb * 32 + hi * 8];
#pragma unroll
      for (int mt = 0; mt < 4; ++mt)
#pragma unroll
        for (int nt = 0; nt < 4; ++nt)
          acc[mt][nt] = MFMA16(af[mt], bfr[nt], acc[mt][nt], 0, 0, 0);
    }
    __syncthreads();
  }

  // Epilogue. C/D layout: row = (lane>>4)*4 + j, col = lane&15 (verified m89/m91).
#pragma unroll
  for (int mt = 0; mt < 4; ++mt) {
#pragma unroll
    for (int nt = 0; nt < 4; ++nt) {
      const int c = n0 + wc * 64 + nt * 16 + lo;
#pragma unroll
      for (int j = 0; j < 4; ++j) {
        const int r = m0 + wr * 64 + mt * 16 + hi * 4 + j;
        float v = acc[mt][nt][j];
        if constexpr (MODE == 1) {
          Cout[(size_t)r * 1024 + c] = v;
        } else if constexpr (MODE == 2) {
          Vb[(size_t)r * 8192 + c] = f2bf(v);  // V^T[e][b*S+s]
        } else {
          const float other = __shfl_xor(v, 1);  // partner column (c^1)
          const int b = r >> 11, s = r & 2047;
          const int h = c >> 6, dd = c & 63;
          float2 cs = rtab[s * 32 + (dd >> 1)];
          float outv = (dd & 1) ? (cs.y * other + cs.x * v)
                                : (cs.x * v - cs.y * other);
          // fold softmax scale AND log2(e) into Q: exp2-domain softmax
          if (z == 0) outv *= 0.18033688012f;  // 0.125 * log2(e)
          unsigned short* dst = (z == 0) ? Qb : Kb;
          dst[((size_t)(b * 16 + h) * 2048 + s) * 64 + dd] = f2bf(outv);
        }
      }
    }
  }
}

// ---------- causal flash attention, swapped-operand 32x32, pipelined ----------
// Grid 512, uniform work: each block runs q-tiles (15-p) then p sequentially
// (2*(15-p)+2 + 2*p+2 = 34 kv-tiles for every block -> zero makespan variance).
// XCD-chunked: bh = (lin&7)*8 + (slot>>3) keeps each (b,h)'s K/V in one L2.
// Double-buffered LDS, one barrier/tile; P^T fragments via permlane32_swap;
// defer-max (T13, THR=8 in exp2 domain) skips most O-rescales.
__global__ __launch_bounds__(256) void attn_k(const unsigned short* __restrict__ Qb,
                                              const unsigned short* __restrict__ Kb,
                                              const unsigned short* __restrict__ VtG,
                                              unsigned short* __restrict__ Ob) {
  __shared__ unsigned short Kl[2][64 * 64];
  __shared__ unsigned short Vl[2][64 * 64];
  const int tid = threadIdx.x;
  const int lane = tid & 63;
  const int w = tid >> 6;
  const int q32 = lane & 31;
  const int hi = lane >> 5;
  const int l7 = lane & 7;
  const int lin = blockIdx.x;           // 0..511
  const int slot = lin >> 3;            // 0..63 within XCD
  const int bh = (lin & 7) * 8 + (slot >> 3);
  const int p = slot & 7;               // pair index 0..7
  const int b = bh >> 4, h = bh & 15;
  const unsigned short* Qp = Qb + (size_t)bh * 2048 * 64;
  const unsigned short* Kp = Kb + (size_t)bh * 2048 * 64;
  const unsigned short* Vg = VtG + (size_t)h * 64 * 8192 + b * 2048;

  const int srow = lane >> 3;           // 0..7: row within 8-row staging chunk
  const int csrc = l7 ^ srow;           // pre-swizzled global chunk (involution)

  // stage one 64x64 K tile + 64x64 V^T tile into buffer `buf`
  auto stage = [&](int kt, int buf) {
#pragma unroll
    for (int i = 0; i < 2; ++i) {
      const int r = w * 16 + i * 8 + srow;
      GLOAD_LDS(Kp + ((size_t)(kt * 64 + r)) * 64 + csrc * 8,
                &Kl[buf][(w * 16 + i * 8) * 64]);
      GLOAD_LDS(Vg + (size_t)r * 8192 + kt * 64 + csrc * 8,
                &Vl[buf][(w * 16 + i * 8) * 64]);
    }
  };

  for (int phase = 0; phase < 2; ++phase) {
    const int qt = phase ? p : 15 - p;
    const int qw = qt * 128 + w * 32;   // wave's q base
    const int qpos = qw + q32;          // this lane's q row

    // Q fragments (B-operand: col=lane&31=q, k = hi*8+e within d-slice)
    bf16x8 qf[4];
#pragma unroll
    for (int ds = 0; ds < 4; ++ds)
      qf[ds] = *(const bf16x8*)&Qp[(size_t)qpos * 64 + ds * 16 + hi * 8];

    f32x16 oa0 = {}, oa1 = {};          // O^T acc (regs=d, lane=q)
    float mrow = -1e30f, lsum = 0.0f;
    const int ntiles = 2 * qt + 2;

    stage(0, 0);
    asm volatile("s_waitcnt vmcnt(0)" ::: "memory");
    __builtin_amdgcn_s_barrier();
    asm volatile("" ::: "memory");

    int cur = 0;
    for (int kt = 0; kt < ntiles; ++kt) {
      if (kt + 1 < ntiles) stage(kt + 1, cur ^ 1);  // prefetch overlaps compute
      const unsigned short* Kc = &Kl[cur][0];
      const unsigned short* Vc = &Vl[cur][0];

      // QK^T swapped: S[kpos][q], kpos blocks 0-31 (s0) and 32-63 (s1)
      f32x16 s0 = {}, s1 = {};
#pragma unroll
      for (int ds = 0; ds < 4; ++ds) {
        const int cc = ((ds * 2 + hi) ^ l7) * 8;
        bf16x8 k0 = *(const bf16x8*)&Kc[q32 * 64 + cc];
        bf16x8 k1 = *(const bf16x8*)&Kc[(32 + q32) * 64 + cc];
        s0 = MFMA32(k0, qf[ds], s0, 0, 0, 0);
        s1 = MFMA32(k1, qf[ds], s1, 0, 0, 0);
      }

      if (kt * 64 + 63 > qw) {          // tile may contain kpos > qpos
#pragma unroll
        for (int r = 0; r < 16; ++r) {
          const int krel = (r & 3) + 8 * (r >> 2) + 4 * hi;
          if (kt * 64 + krel > qpos) s0[r] = -1e30f;
          if (kt * 64 + 32 + krel > qpos) s1[r] = -1e30f;
        }
      }

      // online softmax, exp2 domain (scores pre-scaled by 0.125*log2e via Q)
      float tmax = -1e30f;
#pragma unroll
      for (int r = 0; r < 16; ++r) tmax = fmaxf(tmax, fmaxf(s0[r], s1[r]));
      tmax = fmaxf(tmax, __shfl_xor(tmax, 32));
      if (!__all(tmax - mrow <= 8.0f)) {  // T13 defer-max: rescale only on growth
        const float mnew = fmaxf(mrow, tmax);
        const float alpha = exp2f(mrow - mnew);
        mrow = mnew;
        lsum *= alpha;
#pragma unroll
        for (int r = 0; r < 16; ++r) { oa0[r] *= alpha; oa1[r] *= alpha; }
      }
      float rsum = 0.0f;
#pragma unroll
      for (int r = 0; r < 16; ++r) {
        s0[r] = exp2f(s0[r] - mrow);
        s1[r] = exp2f(s1[r] - mrow);
        rsum += s0[r] + s1[r];
      }
      rsum += __shfl_xor(rsum, 32);
      lsum += rsum;

      // P^T pack: v_cvt_pk pairs, then permlane32_swap builds B-fragments
      // (lo lanes keep own lo-words + partner hi-words; hi lanes converse).
      unsigned int A0[8], A1[8];
#pragma unroll
      for (int i = 0; i < 8; ++i) {
        A0[i] = cvt2(s0[2 * i], s0[2 * i + 1]);
        A1[i] = cvt2(s1[2 * i], s1[2 * i + 1]);
      }
      i32x2 r02 = __builtin_amdgcn_permlane32_swap((int)A0[0], (int)A0[2], 0, 0);
      i32x2 r13 = __builtin_amdgcn_permlane32_swap((int)A0[1], (int)A0[3], 0, 0);
      i32x2 r46 = __builtin_amdgcn_permlane32_swap((int)A0[4], (int)A0[6], 0, 0);
      i32x2 r57 = __builtin_amdgcn_permlane32_swap((int)A0[5], (int)A0[7], 0, 0);
      i32x2 t02 = __builtin_amdgcn_permlane32_swap((int)A1[0], (int)A1[2], 0, 0);
      i32x2 t13 = __builtin_amdgcn_permlane32_swap((int)A1[1], (int)A1[3], 0, 0);
      i32x2 t46 = __builtin_amdgcn_permlane32_swap((int)A1[4], (int)A1[6], 0, 0);
      i32x2 t57 = __builtin_amdgcn_permlane32_swap((int)A1[5], (int)A1[7], 0, 0);
      const u32x4 pw0 = {(unsigned)r02[0], (unsigned)r13[0], (unsigned)r02[1], (unsigned)r13[1]};
      const u32x4 pw1 = {(unsigned)r46[0], (unsigned)r57[0], (unsigned)r46[1], (unsigned)r57[1]};
      const u32x4 pw2 = {(unsigned)t02[0], (unsigned)t13[0], (unsigned)t02[1], (unsigned)t13[1]};
      const u32x4 pw3 = {(unsigned)t46[0], (unsigned)t57[0], (unsigned)t46[1], (unsigned)t57[1]};

      // PV transposed: O^T[d][q] += V^T[d][k-slice] . P^T[k-slice][q]
#pragma unroll
      for (int ks = 0; ks < 4; ++ks) {
        const int cc = ((ks * 2 + hi) ^ l7) * 8;
        bf16x8 v0 = *(const bf16x8*)&Vc[q32 * 64 + cc];
        bf16x8 v1 = *(const bf16x8*)&Vc[(32 + q32) * 64 + cc];
        const u32x4 pwk = (ks == 0) ? pw0 : (ks == 1) ? pw1 : (ks == 2) ? pw2 : pw3;
        bf16x8 pb = __builtin_bit_cast(bf16x8, pwk);
        oa0 = MFMA32(v0, pb, oa0, 0, 0, 0);
        oa1 = MFMA32(v1, pb, oa1, 0, 0, 0);
      }

      // drain next-tile loads (compute covered the latency) + join waves
      asm volatile("s_waitcnt vmcnt(0)" ::: "memory");
      __builtin_amdgcn_s_barrier();
      asm volatile("" ::: "memory");
      cur ^= 1;
    }

    // epilogue: O = (O^T)/l, write [b][s][h*64+d]; regs 4g..4g+3 -> d=8g+4hi+0..3
    const float invl = 1.0f / lsum;
    unsigned short* orow = Ob + ((size_t)(b * 2048 + qpos)) * 1024 + h * 64;
#pragma unroll
    for (int g = 0; g < 4; ++g) {
      uint2 o0, o1;
      o0.x = cvt2(oa0[4 * g + 0] * invl, oa0[4 * g + 1] * invl);
      o0.y = cvt2(oa0[4 * g + 2] * invl, oa0[4 * g + 3] * invl);
      o1.x = cvt2(oa1[4 * g + 0] * invl, oa1[4 * g + 1] * invl);
      o1.y = cvt2(oa1[4 * g + 2] * invl, oa1[4 * g + 3] * invl);
      *(uint2*)&orow[g * 8 + hi * 4] = o0;
      *(uint2*)&orow[32 + g * 8 + hi * 4] = o1;
    }
  }
}

extern "C" void kernel_launch(void* const* d_in, const int* in_sizes, int n_in,
                              void* d_out, int out_size, void* d_ws, size_t ws_size,
                              hipStream_t stream) {
  const float* x  = (const float*)d_in[0];
  const float* wq = (const float*)d_in[1];
  const float* wk = (const float*)d_in[2];
  const float* wv = (const float*)d_in[3];
  const float* wo = (const float*)d_in[4];
  const int* pos  = (const int*)d_in[5];

  char* ws = (char*)d_ws;
  unsigned short* xb  = (unsigned short*)(ws);               // 8192x1024 bf16
  unsigned short* wb  = (unsigned short*)(ws + 16777216);    // 4x 1024x1024 bf16
  unsigned short* Qb  = (unsigned short*)(ws + 25165824);    // [b][h][s][d] bf16
  unsigned short* Kb  = (unsigned short*)(ws + 41943040);    // [b][h][s][d] bf16
  unsigned short* Vt  = (unsigned short*)(ws + 58720256);    // V^T [e][b*S+s] bf16
  unsigned short* Ob  = (unsigned short*)(ws + 75497472);    // [b][s][e] bf16
  float2* tab         = (float2*)(ws + 92274688);            // [2048][32] cos/sin

  cast_bf16_k<<<4096, 256, 0, stream>>>(x, xb, 1048576);
  cast_bf16_k<<<512, 256, 0, stream>>>(wq, wb + 0 * 1048576, 131072);
  cast_bf16_k<<<512, 256, 0, stream>>>(wk, wb + 1 * 1048576, 131072);
  cast_bf16_k<<<512, 256, 0, stream>>>(wv, wb + 2 * 1048576, 131072);
  cast_bf16_k<<<512, 256, 0, stream>>>(wo, wb + 3 * 1048576, 131072);
  rope_tab_k<<<256, 256, 0, stream>>>(pos, tab);
  gemm_bt<0><<<dim3(64, 8, 2), 256, 0, stream>>>(xb, wb, Qb, Kb, nullptr, nullptr, tab);
  gemm_bt<2><<<dim3(8, 64, 1), 256, 0, stream>>>(wb + 2 * 1048576, xb, nullptr,
                                                 nullptr, Vt, nullptr, tab);
  attn_k<<<dim3(512), 256, 0, stream>>>(Qb, Kb, Vt, Ob);
  gemm_bt<1><<<dim3(64, 8, 1), 256, 0, stream>>>(Ob, wb + 3 * 1048576, nullptr,
                                                 nullptr, nullptr, (float*)d_out, tab);
}

// Round 10
// 283.821 us; speedup vs baseline: 2.0494x; 1.0772x over previous
//
#include <hip/hip_runtime.h>
#include <hip/hip_bf16.h>

typedef __attribute__((ext_vector_type(8))) __bf16 bf16x8;
typedef __attribute__((ext_vector_type(2))) __bf16 bf16x2;
typedef __attribute__((ext_vector_type(2))) float f32x2;
typedef __attribute__((ext_vector_type(16))) float f32x16;
typedef __attribute__((ext_vector_type(4))) unsigned int u32x4;
typedef __attribute__((ext_vector_type(2))) int i32x2;

#define MFMA32 __builtin_amdgcn_mfma_f32_32x32x16_bf16
#define GLOAD_LDS(g, l)                                                      \
  __builtin_amdgcn_global_load_lds(                                          \
      (const __attribute__((address_space(1))) void*)(g),                    \
      (__attribute__((address_space(3))) void*)(l), 16, 0, 0)

static __device__ __forceinline__ unsigned short f2bf(float f) {
  return __builtin_bit_cast(unsigned short, (__bf16)f);  // RNE hw cvt
}
static __device__ __forceinline__ unsigned int cvt2(float a, float b) {
  f32x2 t = {a, b};
  return __builtin_bit_cast(unsigned int, __builtin_convertvector(t, bf16x2));
}

// ---------- fp32 -> bf16 cast, 8 elems/thread ----------
__global__ __launch_bounds__(256) void cast_bf16_k(const float* __restrict__ in,
                                                   unsigned short* __restrict__ out,
                                                   int n8) {
  int i = blockIdx.x * 256 + threadIdx.x;
  if (i >= n8) return;
  const float4* p = (const float4*)in + (size_t)i * 2;
  float4 a = p[0], b = p[1];
  uint4 r;
  r.x = cvt2(a.x, a.y); r.y = cvt2(a.z, a.w);
  r.z = cvt2(b.x, b.y); r.w = cvt2(b.z, b.w);
  *((uint4*)out + i) = r;
}

// ---------- RoPE cos/sin table: [2048][32] float2 ----------
__global__ __launch_bounds__(256) void rope_tab_k(const int* __restrict__ pos,
                                                  float2* __restrict__ tab) {
  int t = blockIdx.x * 256 + threadIdx.x;  // 65536 total
  int s = t >> 5, k = t & 31;
  float p = (float)pos[s];
  float inv = powf(10000.0f, -(float)(2 * k) / 64.0f);
  float ang = p * inv;
  tab[t] = make_float2(cosf(ang), sinf(ang));
}

// ---------- bf16 GEMM: C[M][N] = A[M][K] * B^T, B given as [N][K] ----------
// 128x128 tile, 4 waves (2x2), per-wave 64x64 via 2x2 MFMA32 fragments.
// LDS chunk-XOR swizzled (T2): stage source chunk = (lane&7)^sr, read chunk
// ^= row&7 — same involution attn_k validated (rule #21 both-sides).
// MODE 0: A=x_bf16 (M=8192), z in {0,1} selects w_{q,k}; epilogue RoPE,
//         Q *= 0.125*log2(e) (exp2 softmax domain), bf16 scatter to [b][h][s][d].
// MODE 1: A=O_bf16, W=w_o_bf16; fp32 store to Cout (ldc=1024).
// MODE 2: A=w_v (M=1024), W=x_bf16 (N=8192); bf16 store V^T[e][b*S+s] (ldc=8192).
template <int MODE>
__global__ __launch_bounds__(256) void gemm_bt(
    const unsigned short* __restrict__ A, const unsigned short* __restrict__ W,
    unsigned short* __restrict__ Qb, unsigned short* __restrict__ Kb,
    unsigned short* __restrict__ Vb, float* __restrict__ Cout,
    const float2* __restrict__ rtab) {
  __shared__ unsigned short As[128 * 64];
  __shared__ unsigned short Bs[128 * 64];
  const int tid = threadIdx.x;
  const int lane = tid & 63;
  const int w = tid >> 6;          // wave 0..3
  const int wr = w >> 1, wc = w & 1;
  const int q32 = lane & 31;
  const int hi = lane >> 5;        // 0/1
  const int l7 = lane & 7;
  const int m0 = blockIdx.x * 128;
  const int n0 = blockIdx.y * 128;
  const int z = blockIdx.z;
  const unsigned short* Bmat = W + (size_t)z * 1024 * 1024;

  const int sr = lane >> 3;        // staging row within 8-row chunk
  const int csrc = l7 ^ sr;        // pre-swizzled source chunk (involution)

  f32x16 acc00 = {}, acc01 = {}, acc10 = {}, acc11 = {};

  for (int kt = 0; kt < 16; ++kt) {
    const int kofs = kt * 64;
#pragma unroll
    for (int c = 0; c < 4; ++c) {
      const int rowA = c * 32 + w * 8;  // multiple of 8 -> (row&7)=sr
      GLOAD_LDS(A + (size_t)(m0 + rowA + sr) * 1024 + kofs + csrc * 8,
                &As[rowA * 64]);
      GLOAD_LDS(Bmat + (size_t)(n0 + rowA + sr) * 1024 + kofs + csrc * 8,
                &Bs[rowA * 64]);
    }
    __syncthreads();
#pragma unroll
    for (int kk = 0; kk < 4; ++kk) {
      const int cc = ((kk * 2 + hi) ^ l7) * 8;  // swizzled read (row&7 = l7)
      bf16x8 a0 = *(const bf16x8*)&As[(wr * 64 + q32) * 64 + cc];
      bf16x8 a1 = *(const bf16x8*)&As[(wr * 64 + 32 + q32) * 64 + cc];
      bf16x8 b0 = *(const bf16x8*)&Bs[(wc * 64 + q32) * 64 + cc];
      bf16x8 b1 = *(const bf16x8*)&Bs[(wc * 64 + 32 + q32) * 64 + cc];
      acc00 = MFMA32(a0, b0, acc00, 0, 0, 0);
      acc01 = MFMA32(a0, b1, acc01, 0, 0, 0);
      acc10 = MFMA32(a1, b0, acc10, 0, 0, 0);
      acc11 = MFMA32(a1, b1, acc11, 0, 0, 0);
    }
    __syncthreads();
  }

  // Epilogue. MFMA32 C/D: col = lane&31, row = (r&3)+8*(r>>2)+4*hi (validated
  // on-HW by attn_k's causal mask since round 4).
#pragma unroll
  for (int mt = 0; mt < 2; ++mt) {
#pragma unroll
    for (int nt = 0; nt < 2; ++nt) {
      const f32x16 av = (mt == 0) ? (nt == 0 ? acc00 : acc01)
                                  : (nt == 0 ? acc10 : acc11);
      const int c = n0 + wc * 64 + nt * 32 + q32;
#pragma unroll
      for (int r = 0; r < 16; ++r) {
        const int rr = m0 + wr * 64 + mt * 32 + (r & 3) + 8 * (r >> 2) + 4 * hi;
        float v = av[r];
        if constexpr (MODE == 1) {
          Cout[(size_t)rr * 1024 + c] = v;
        } else if constexpr (MODE == 2) {
          Vb[(size_t)rr * 8192 + c] = f2bf(v);  // V^T[e][b*S+s]
        } else {
          const float other = __shfl_xor(v, 1);  // partner column (c^1)
          const int b = rr >> 11, s = rr & 2047;
          const int h = c >> 6, dd = c & 63;
          float2 cs = rtab[s * 32 + (dd >> 1)];
          float outv = (dd & 1) ? (cs.y * other + cs.x * v)
                                : (cs.x * v - cs.y * other);
          // fold softmax scale AND log2(e) into Q: exp2-domain softmax
          if (z == 0) outv *= 0.18033688012f;  // 0.125 * log2(e)
          unsigned short* dst = (z == 0) ? Qb : Kb;
          dst[((size_t)(b * 16 + h) * 2048 + s) * 64 + dd] = f2bf(outv);
        }
      }
    }
  }
}

// ---------- causal flash attention, swapped-operand 32x32, pipelined ----------
// Grid 512, uniform work: each block runs q-tiles (15-p) then p sequentially
// (2*(15-p)+2 + 2*p+2 = 34 kv-tiles for every block -> zero makespan variance).
// XCD-chunked: bh = (lin&7)*8 + (slot>>3) keeps each (b,h)'s K/V in one L2.
// Double-buffered LDS, one barrier/tile; P^T fragments via permlane32_swap;
// defer-max (T13, THR=8 in exp2 domain) skips most O-rescales.
__global__ __launch_bounds__(256) void attn_k(const unsigned short* __restrict__ Qb,
                                              const unsigned short* __restrict__ Kb,
                                              const unsigned short* __restrict__ VtG,
                                              unsigned short* __restrict__ Ob) {
  __shared__ unsigned short Kl[2][64 * 64];
  __shared__ unsigned short Vl[2][64 * 64];
  const int tid = threadIdx.x;
  const int lane = tid & 63;
  const int w = tid >> 6;
  const int q32 = lane & 31;
  const int hi = lane >> 5;
  const int l7 = lane & 7;
  const int lin = blockIdx.x;           // 0..511
  const int slot = lin >> 3;            // 0..63 within XCD
  const int bh = (lin & 7) * 8 + (slot >> 3);
  const int p = slot & 7;               // pair index 0..7
  const int b = bh >> 4, h = bh & 15;
  const unsigned short* Qp = Qb + (size_t)bh * 2048 * 64;
  const unsigned short* Kp = Kb + (size_t)bh * 2048 * 64;
  const unsigned short* Vg = VtG + (size_t)h * 64 * 8192 + b * 2048;

  const int srow = lane >> 3;           // 0..7: row within 8-row staging chunk
  const int csrc = l7 ^ srow;           // pre-swizzled global chunk (involution)

  // stage one 64x64 K tile + 64x64 V^T tile into buffer `buf`
  auto stage = [&](int kt, int buf) {
#pragma unroll
    for (int i = 0; i < 2; ++i) {
      const int r = w * 16 + i * 8 + srow;
      GLOAD_LDS(Kp + ((size_t)(kt * 64 + r)) * 64 + csrc * 8,
                &Kl[buf][(w * 16 + i * 8) * 64]);
      GLOAD_LDS(Vg + (size_t)r * 8192 + kt * 64 + csrc * 8,
                &Vl[buf][(w * 16 + i * 8) * 64]);
    }
  };

  for (int phase = 0; phase < 2; ++phase) {
    const int qt = phase ? p : 15 - p;
    const int qw = qt * 128 + w * 32;   // wave's q base
    const int qpos = qw + q32;          // this lane's q row

    // Q fragments (B-operand: col=lane&31=q, k = hi*8+e within d-slice)
    bf16x8 qf[4];
#pragma unroll
    for (int ds = 0; ds < 4; ++ds)
      qf[ds] = *(const bf16x8*)&Qp[(size_t)qpos * 64 + ds * 16 + hi * 8];

    f32x16 oa0 = {}, oa1 = {};          // O^T acc (regs=d, lane=q)
    float mrow = -1e30f, lsum = 0.0f;
    const int ntiles = 2 * qt + 2;

    stage(0, 0);
    asm volatile("s_waitcnt vmcnt(0)" ::: "memory");
    __builtin_amdgcn_s_barrier();
    asm volatile("" ::: "memory");

    int cur = 0;
    for (int kt = 0; kt < ntiles; ++kt) {
      if (kt + 1 < ntiles) stage(kt + 1, cur ^ 1);  // prefetch overlaps compute
      const unsigned short* Kc = &Kl[cur][0];
      const unsigned short* Vc = &Vl[cur][0];

      // QK^T swapped: S[kpos][q], kpos blocks 0-31 (s0) and 32-63 (s1)
      f32x16 s0 = {}, s1 = {};
#pragma unroll
      for (int ds = 0; ds < 4; ++ds) {
        const int cc = ((ds * 2 + hi) ^ l7) * 8;
        bf16x8 k0 = *(const bf16x8*)&Kc[q32 * 64 + cc];
        bf16x8 k1 = *(const bf16x8*)&Kc[(32 + q32) * 64 + cc];
        s0 = MFMA32(k0, qf[ds], s0, 0, 0, 0);
        s1 = MFMA32(k1, qf[ds], s1, 0, 0, 0);
      }

      if (kt * 64 + 63 > qw) {          // tile may contain kpos > qpos
#pragma unroll
        for (int r = 0; r < 16; ++r) {
          const int krel = (r & 3) + 8 * (r >> 2) + 4 * hi;
          if (kt * 64 + krel > qpos) s0[r] = -1e30f;
          if (kt * 64 + 32 + krel > qpos) s1[r] = -1e30f;
        }
      }

      // online softmax, exp2 domain (scores pre-scaled by 0.125*log2e via Q)
      float tmax = -1e30f;
#pragma unroll
      for (int r = 0; r < 16; ++r) tmax = fmaxf(tmax, fmaxf(s0[r], s1[r]));
      tmax = fmaxf(tmax, __shfl_xor(tmax, 32));
      if (!__all(tmax - mrow <= 8.0f)) {  // T13 defer-max: rescale only on growth
        const float mnew = fmaxf(mrow, tmax);
        const float alpha = exp2f(mrow - mnew);
        mrow = mnew;
        lsum *= alpha;
#pragma unroll
        for (int r = 0; r < 16; ++r) { oa0[r] *= alpha; oa1[r] *= alpha; }
      }
      float rsum = 0.0f;
#pragma unroll
      for (int r = 0; r < 16; ++r) {
        s0[r] = exp2f(s0[r] - mrow);
        s1[r] = exp2f(s1[r] - mrow);
        rsum += s0[r] + s1[r];
      }
      rsum += __shfl_xor(rsum, 32);
      lsum += rsum;

      // P^T pack: v_cvt_pk pairs, then permlane32_swap builds B-fragments
      // (lo lanes keep own lo-words + partner hi-words; hi lanes converse).
      unsigned int A0[8], A1[8];
#pragma unroll
      for (int i = 0; i < 8; ++i) {
        A0[i] = cvt2(s0[2 * i], s0[2 * i + 1]);
        A1[i] = cvt2(s1[2 * i], s1[2 * i + 1]);
      }
      i32x2 r02 = __builtin_amdgcn_permlane32_swap((int)A0[0], (int)A0[2], 0, 0);
      i32x2 r13 = __builtin_amdgcn_permlane32_swap((int)A0[1], (int)A0[3], 0, 0);
      i32x2 r46 = __builtin_amdgcn_permlane32_swap((int)A0[4], (int)A0[6], 0, 0);
      i32x2 r57 = __builtin_amdgcn_permlane32_swap((int)A0[5], (int)A0[7], 0, 0);
      i32x2 t02 = __builtin_amdgcn_permlane32_swap((int)A1[0], (int)A1[2], 0, 0);
      i32x2 t13 = __builtin_amdgcn_permlane32_swap((int)A1[1], (int)A1[3], 0, 0);
      i32x2 t46 = __builtin_amdgcn_permlane32_swap((int)A1[4], (int)A1[6], 0, 0);
      i32x2 t57 = __builtin_amdgcn_permlane32_swap((int)A1[5], (int)A1[7], 0, 0);
      const u32x4 pw0 = {(unsigned)r02[0], (unsigned)r13[0], (unsigned)r02[1], (unsigned)r13[1]};
      const u32x4 pw1 = {(unsigned)r46[0], (unsigned)r57[0], (unsigned)r46[1], (unsigned)r57[1]};
      const u32x4 pw2 = {(unsigned)t02[0], (unsigned)t13[0], (unsigned)t02[1], (unsigned)t13[1]};
      const u32x4 pw3 = {(unsigned)t46[0], (unsigned)t57[0], (unsigned)t46[1], (unsigned)t57[1]};

      // PV transposed: O^T[d][q] += V^T[d][k-slice] . P^T[k-slice][q]
#pragma unroll
      for (int ks = 0; ks < 4; ++ks) {
        const int cc = ((ks * 2 + hi) ^ l7) * 8;
        bf16x8 v0 = *(const bf16x8*)&Vc[q32 * 64 + cc];
        bf16x8 v1 = *(const bf16x8*)&Vc[(32 + q32) * 64 + cc];
        const u32x4 pwk = (ks == 0) ? pw0 : (ks == 1) ? pw1 : (ks == 2) ? pw2 : pw3;
        bf16x8 pb = __builtin_bit_cast(bf16x8, pwk);
        oa0 = MFMA32(v0, pb, oa0, 0, 0, 0);
        oa1 = MFMA32(v1, pb, oa1, 0, 0, 0);
      }

      // drain next-tile loads (compute covered the latency) + join waves
      asm volatile("s_waitcnt vmcnt(0)" ::: "memory");
      __builtin_amdgcn_s_barrier();
      asm volatile("" ::: "memory");
      cur ^= 1;
    }

    // epilogue: O = (O^T)/l, write [b][s][h*64+d]; regs 4g..4g+3 -> d=8g+4hi+0..3
    const float invl = 1.0f / lsum;
    unsigned short* orow = Ob + ((size_t)(b * 2048 + qpos)) * 1024 + h * 64;
#pragma unroll
    for (int g = 0; g < 4; ++g) {
      uint2 o0, o1;
      o0.x = cvt2(oa0[4 * g + 0] * invl, oa0[4 * g + 1] * invl);
      o0.y = cvt2(oa0[4 * g + 2] * invl, oa0[4 * g + 3] * invl);
      o1.x = cvt2(oa1[4 * g + 0] * invl, oa1[4 * g + 1] * invl);
      o1.y = cvt2(oa1[4 * g + 2] * invl, oa1[4 * g + 3] * invl);
      *(uint2*)&orow[g * 8 + hi * 4] = o0;
      *(uint2*)&orow[32 + g * 8 + hi * 4] = o1;
    }
  }
}

extern "C" void kernel_launch(void* const* d_in, const int* in_sizes, int n_in,
                              void* d_out, int out_size, void* d_ws, size_t ws_size,
                              hipStream_t stream) {
  const float* x  = (const float*)d_in[0];
  const float* wq = (const float*)d_in[1];
  const float* wk = (const float*)d_in[2];
  const float* wv = (const float*)d_in[3];
  const float* wo = (const float*)d_in[4];
  const int* pos  = (const int*)d_in[5];

  char* ws = (char*)d_ws;
  unsigned short* xb  = (unsigned short*)(ws);               // 8192x1024 bf16
  unsigned short* wb  = (unsigned short*)(ws + 16777216);    // 4x 1024x1024 bf16
  unsigned short* Qb  = (unsigned short*)(ws + 25165824);    // [b][h][s][d] bf16
  unsigned short* Kb  = (unsigned short*)(ws + 41943040);    // [b][h][s][d] bf16
  unsigned short* Vt  = (unsigned short*)(ws + 58720256);    // V^T [e][b*S+s] bf16
  unsigned short* Ob  = (unsigned short*)(ws + 75497472);    // [b][s][e] bf16
  float2* tab         = (float2*)(ws + 92274688);            // [2048][32] cos/sin

  cast_bf16_k<<<4096, 256, 0, stream>>>(x, xb, 1048576);
  cast_bf16_k<<<512, 256, 0, stream>>>(wq, wb + 0 * 1048576, 131072);
  cast_bf16_k<<<512, 256, 0, stream>>>(wk, wb + 1 * 1048576, 131072);
  cast_bf16_k<<<512, 256, 0, stream>>>(wv, wb + 2 * 1048576, 131072);
  cast_bf16_k<<<512, 256, 0, stream>>>(wo, wb + 3 * 1048576, 131072);
  rope_tab_k<<<256, 256, 0, stream>>>(pos, tab);
  gemm_bt<0><<<dim3(64, 8, 2), 256, 0, stream>>>(xb, wb, Qb, Kb, nullptr, nullptr, tab);
  gemm_bt<2><<<dim3(8, 64, 1), 256, 0, stream>>>(wb + 2 * 1048576, xb, nullptr,
                                                 nullptr, Vt, nullptr, tab);
  attn_k<<<dim3(512), 256, 0, stream>>>(Qb, Kb, Vt, Ob);
  gemm_bt<1><<<dim3(64, 8, 1), 256, 0, stream>>>(Ob, wb + 3 * 1048576, nullptr,
                                                 nullptr, nullptr, (float*)d_out, tab);
}